// Round 3
// baseline (3182.075 us; speedup 1.0000x reference)
//
#include <hip/hip_runtime.h>
#include <hip/hip_bf16.h>

#define DEV __device__ __forceinline__

constexpr int B_ = 256;   // batch
constexpr int T_ = 512;   // time
constexpr int H_ = 128;   // GRU units
constexpr int K_ = 256;   // input dim per layer (D = 2H = 256 for all layers)
constexpr int G_ = 384;   // 3H
constexpr int M_ = B_ * T_;
constexpr int LDSROW = 72;  // ushorts per LDS tile row (64 data + 8 pad)

using bf16 = __hip_bfloat16;
typedef short bf16x8 __attribute__((ext_vector_type(8)));
typedef float f32x4 __attribute__((ext_vector_type(4)));
typedef float f32x2 __attribute__((ext_vector_type(2)));

DEV float tof(float x) { return x; }
DEV float tof(bf16 x) { return __bfloat162float(x); }
DEV void stor(float* p, float v) { *p = v; }
DEV void stor(bf16* p, float v) { *p = __float2bfloat16(v); }

// float -> bf16 bits, round-to-nearest-even
DEV unsigned short f2bs(float f) {
  union { float f; unsigned u; } v;
  v.f = f;
  unsigned r = (v.u + 0x7FFFu + ((v.u >> 16) & 1u)) >> 16;
  return (unsigned short)r;
}
DEV float bs2f(unsigned short s) {
  union { unsigned u; float f; } v;
  v.u = ((unsigned)s) << 16;
  return v.f;
}

DEV float fsigmoid(float x) { return 1.f / (1.f + __expf(-x)); }
DEV float ftanh(float x) {
  x = fminf(20.f, fmaxf(-20.f, x));
  float e = __expf(-2.f * x);
  return (1.f - e) / (1.f + e);
}

// Barrier draining only LDS traffic (lgkmcnt), not global loads/stores.
DEV void barrier_lds() {
  asm volatile("s_waitcnt lgkmcnt(0)\n\ts_barrier" ::: "memory");
}

// Pin a float4 into VGPRs (opaque to the optimizer).
DEV void pin4(float4& v) {
  asm volatile("" : "+v"(v.x), "+v"(v.y), "+v"(v.z), "+v"(v.w));
}

DEV f32x4 mfma16(bf16x8 a, bf16x8 b, f32x4 c) {
  return __builtin_amdgcn_mfma_f32_16x16x32_bf16(a, b, c, 0, 0, 0);
}

// ---------------------------------------------------------------------------
// convX: split fp32 x[M,256] into bf16 hi/lo arrays (layer-0 GEMM input).
// ---------------------------------------------------------------------------
__global__ __launch_bounds__(256) void convX_kernel(
    const float* __restrict__ x, ushort* __restrict__ hiA,
    ushort* __restrict__ loA) {
  const int n4 = M_ * K_ / 4;
  for (int idx = blockIdx.x * blockDim.x + threadIdx.x; idx < n4;
       idx += gridDim.x * blockDim.x) {
    float4 v = ((const float4*)x)[idx];
    ushort4 h, l;
    h.x = f2bs(v.x); l.x = f2bs(v.x - bs2f(h.x));
    h.y = f2bs(v.y); l.y = f2bs(v.y - bs2f(h.y));
    h.z = f2bs(v.z); l.z = f2bs(v.z - bs2f(h.z));
    h.w = f2bs(v.w); l.w = f2bs(v.w - bs2f(h.w));
    ((ushort4*)hiA)[idx] = h;
    ((ushort4*)loA)[idx] = l;
  }
}

// ---------------------------------------------------------------------------
// convW: W[dir][256][384] fp32 -> W^T hi/lo bf16 [768 ncol][256 k].
// ---------------------------------------------------------------------------
__global__ __launch_bounds__(256) void convW_kernel(
    const float* __restrict__ W, ushort* __restrict__ WhiT,
    ushort* __restrict__ WloT) {
  const int ncol = blockIdx.x;           // 0..767
  const int dir = ncol / G_, j = ncol % G_;
  const int k = threadIdx.x;             // 0..255
  const float f = W[((size_t)dir * K_ + k) * G_ + j];
  const unsigned short hi = f2bs(f);
  WhiT[(size_t)ncol * K_ + k] = hi;
  WloT[(size_t)ncol * K_ + k] = f2bs(f - bs2f(hi));
}

// ---------------------------------------------------------------------------
// gemm3: C[M,768] = A[M,256] @ W^T' + bias, bf16 hi/lo 3-term split MFMA.
// ---------------------------------------------------------------------------
template <typename XT>
__global__ __launch_bounds__(256, 2) void gemm3_kernel(
    const ushort* __restrict__ Ahi, const ushort* __restrict__ Alo,
    const ushort* __restrict__ WhiT, const ushort* __restrict__ WloT,
    const float* __restrict__ bbias, XT* __restrict__ xp) {
  const int m0 = blockIdx.x * 128;
  const int n0 = blockIdx.y * 128;
  const int tid = threadIdx.x;
  const int w = tid >> 6, lane = tid & 63;
  const int wm = w >> 1, wn = w & 1;
  const int col = lane & 15, quad = lane >> 4;

  __shared__ __align__(16) ushort AH[128 * LDSROW];
  __shared__ __align__(16) ushort AL[128 * LDSROW];
  __shared__ __align__(16) ushort BH[128 * LDSROW];
  __shared__ __align__(16) ushort BL[128 * LDSROW];

  f32x4 acc[4][4];
#pragma unroll
  for (int i = 0; i < 4; ++i)
#pragma unroll
    for (int n = 0; n < 4; ++n) acc[i][n] = (f32x4){0.f, 0.f, 0.f, 0.f};

  const ushort* gsrc = (w == 0) ? Ahi : (w == 1) ? Alo : (w == 2) ? WhiT : WloT;
  ushort* lds = (w == 0) ? AH : (w == 1) ? AL : (w == 2) ? BH : BL;
  const int rbase = (w < 2) ? m0 : n0;

  for (int kb = 0; kb < K_; kb += 64) {
#pragma unroll
    for (int q = 0; q < 16; ++q) {
      const int slot = q * 64 + lane;
      const int r = slot >> 3, s = slot & 7;
      bf16x8 v = *(const bf16x8*)(gsrc + (size_t)(rbase + r) * K_ + kb + s * 8);
      *(bf16x8*)&lds[r * LDSROW + s * 8] = v;
    }
    __syncthreads();
#pragma unroll
    for (int z = 0; z < 2; ++z) {
      const int cc8 = (z * 4 + quad) * 8;
      bf16x8 ah[4], al[4], bh[4], bl[4];
#pragma unroll
      for (int i = 0; i < 4; ++i) {
        const int row = wm * 64 + i * 16 + col;
        ah[i] = *(const bf16x8*)&AH[row * LDSROW + cc8];
        al[i] = *(const bf16x8*)&AL[row * LDSROW + cc8];
      }
#pragma unroll
      for (int n = 0; n < 4; ++n) {
        const int row = wn * 64 + n * 16 + col;
        bh[n] = *(const bf16x8*)&BH[row * LDSROW + cc8];
        bl[n] = *(const bf16x8*)&BL[row * LDSROW + cc8];
      }
#pragma unroll
      for (int i = 0; i < 4; ++i)
#pragma unroll
        for (int n = 0; n < 4; ++n) {
          acc[i][n] = mfma16(ah[i], bh[n], acc[i][n]);
          acc[i][n] = mfma16(al[i], bh[n], acc[i][n]);
          acc[i][n] = mfma16(ah[i], bl[n], acc[i][n]);
        }
    }
    __syncthreads();
  }

  const int dir = (n0 >= G_) ? 1 : 0;
#pragma unroll
  for (int n = 0; n < 4; ++n) {
    const int ncol = n0 + wn * 64 + n * 16 + col;
    const int g = ncol - dir * G_;
    const float bv = bbias[dir * 2 * G_ + g];
#pragma unroll
    for (int i = 0; i < 4; ++i) {
      const int mb = m0 + wm * 64 + i * 16 + quad * 4;
#pragma unroll
      for (int r = 0; r < 4; ++r) {
        const int m = mb + r;
        const int bb = m >> 9;          // T_ = 512
        const int t = m & (T_ - 1);
        stor(xp + ((size_t)(dir * T_ + t) * B_ + bb) * G_ + g,
             acc[i][n][r] + bv);
      }
    }
  }
}

DEV float4 ldU4(const float* U, int col, int k0) {
  float4 v;
  v.x = U[(size_t)(k0 + 0) * G_ + col];
  v.y = U[(size_t)(k0 + 1) * G_ + col];
  v.z = U[(size_t)(k0 + 2) * G_ + col];
  v.w = U[(size_t)(k0 + 3) * G_ + col];
  return v;
}

// ---------------------------------------------------------------------------
// Recurrence, v2. Grid (256, 2): ONE sequence per block, 384 threads.
// Theory: v1 (768 thr, 2 seqs/block) spent 48/130 VALU ops per thread per
// step on an 8-lane DPP butterfly, and with 1 block/CU both per-step barriers
// stalled the whole CU (VALUBusy 63%). v2: thread c owns output column c with
// the FULL k=128 dot -> zero cross-lane reduction (64 v_pk_fma_f32, 4 chains).
// h is wave-uniform -> 32 broadcast ds_read_b128 (conflict-free). U column in
// 32 pinned float4s (~128 VGPR). Grid 512 -> 2 blocks/CU so one block's gate/
// barrier dead-time is covered by the other block's dot phase. Gate thread's
// own h stays in a register (hprev); hbuf double-buffered so only lgkmcnt
// barriers are needed. waves_per_eu min=3 (no max-pin: let regalloc spill
// visibly rather than force it).
// ---------------------------------------------------------------------------
template <typename XT, bool LAST>
__global__ __attribute__((amdgpu_flat_work_group_size(384, 384),
                          amdgpu_waves_per_eu(3))) void rec_kernel(
    const XT* __restrict__ xp, const float* __restrict__ Ubase,
    const float* __restrict__ bbase, ushort* __restrict__ seqH,
    ushort* __restrict__ seqL, float* __restrict__ fin) {
  const int dir = blockIdx.y;
  const int b = blockIdx.x;
  const float* U = Ubase + dir * (H_ * G_);
  const float* bh = bbase + dir * (2 * G_) + G_;
  const int c = threadIdx.x;        // output column 0..383
  const bool gateT = c < H_;

  __shared__ __align__(16) float hbuf[2][H_];
  __shared__ float rec_s[G_];

  // U column c: 128 floats in 32 pinned float4s (static indices only).
  float4 u[32];
#pragma unroll
  for (int i = 0; i < 32; ++i) {
    u[i] = ldU4(U, c, 4 * i);
    pin4(u[i]);
  }

  const float bmine = bh[c];

  if (gateT) {
    hbuf[0][c] = 0.f;
    hbuf[1][c] = 0.f;
  }

  const XT* xbase = xp + (size_t)(dir * T_) * B_ * G_;

  XT xzc{}, xrc{}, xhc{};
  {
    const int t0 = dir ? (T_ - 1) : 0;
    if (gateT) {
      const XT* xr_ = xbase + ((size_t)t0 * B_ + b) * G_ + c;
      xzc = xr_[0];
      xrc = xr_[H_];
      xhc = xr_[2 * H_];
    }
  }
  float hprev = 0.f;   // gate thread's own h, carried in-register
  barrier_lds();

  for (int it = 0; it < T_; ++it) {
    const int t = dir ? (T_ - 1 - it) : it;
    const int cur = it & 1, nxt = cur ^ 1;

    // --- prefetch xp for step it+1 (hidden under the dot phase) ---
    XT xzn = xzc, xrn = xrc, xhn = xhc;
    if (gateT && (it + 1 < T_)) {
      const int tn = dir ? (t - 1) : (t + 1);
      const XT* xr_ = xbase + ((size_t)tn * B_ + b) * G_ + c;
      xzn = xr_[0];
      xrn = xr_[H_];
      xhn = xr_[2 * H_];
    }

    // --- dot phase: full-k column dot, no cross-lane reduction ---
    f32x2 a0 = {0.f, 0.f}, a1 = {0.f, 0.f}, a2 = {0.f, 0.f}, a3 = {0.f, 0.f};
#pragma unroll
    for (int i = 0; i < 32; i += 2) {
      const float4 h0 = *(const float4*)&hbuf[cur][i * 4];
      const float4 h1 = *(const float4*)&hbuf[cur][i * 4 + 4];
      const f32x2* hp0 = (const f32x2*)&h0;
      const f32x2* hp1 = (const f32x2*)&h1;
      const f32x2* up0 = (const f32x2*)&u[i];
      const f32x2* up1 = (const f32x2*)&u[i + 1];
      a0 = __builtin_elementwise_fma(hp0[0], up0[0], a0);
      a1 = __builtin_elementwise_fma(hp0[1], up0[1], a1);
      a2 = __builtin_elementwise_fma(hp1[0], up1[0], a2);
      a3 = __builtin_elementwise_fma(hp1[1], up1[1], a3);
    }
    a0 += a1;
    a2 += a3;
    a0 += a2;
    rec_s[c] = a0.x + a0.y + bmine;
    barrier_lds();

    // --- gate phase (first 128 threads; other block on the CU overlaps) ---
    if (gateT) {
      const float xz = tof(xzc);
      const float xr = tof(xrc);
      const float xh = tof(xhc);
      const float rz = rec_s[c];
      const float rr = rec_s[H_ + c];
      const float rh = rec_s[2 * H_ + c];
      const float z = fsigmoid(xz + rz);
      const float r = fsigmoid(xr + rr);
      const float hh = ftanh(xh + r * rh);
      const float hn = z * hprev + (1.f - z) * hh;
      hprev = hn;
      hbuf[nxt][c] = hn;
      if constexpr (!LAST) {
        const size_t sidx = ((size_t)b * T_ + t) * (2 * H_) + dir * H_ + c;
        const unsigned short hi = f2bs(hn);
        seqH[sidx] = hi;
        seqL[sidx] = f2bs(hn - bs2f(hi));
      }
      xzc = xzn;
      xrc = xrn;
      xhc = xhn;
    }
    barrier_lds();
  }

  if constexpr (LAST) {
    if (gateT) fin[(size_t)b * (2 * H_) + dir * H_ + c] = hprev;
  }
}

// ---------------------------------------------------------------------------
// Dense head: out[b] = sigmoid(fin[b][:] . Wd + bd)
// ---------------------------------------------------------------------------
__global__ void dense_kernel(const float* __restrict__ fin,
                             const float* __restrict__ Wd,
                             const float* __restrict__ bd,
                             float* __restrict__ out) {
  __shared__ float w[2 * H_];
  const int tid = threadIdx.x;
  w[tid] = Wd[tid];
  __syncthreads();
  float s = bd[0];
  const float* row = fin + tid * (2 * H_);
#pragma unroll 8
  for (int jj = 0; jj < 2 * H_; ++jj) s = fmaf(row[jj], w[jj], s);
  out[tid] = 1.f / (1.f + __expf(-s));
}

// ---------------------------------------------------------------------------
template <typename XT>
static void run_model(const float* x, const float* Ws, const float* Us,
                      const float* bs, const float* Wd, const float* bd,
                      float* out, char* ws, hipStream_t stream) {
  const size_t xpB = (size_t)2 * T_ * B_ * G_ * sizeof(XT);
  const size_t seqB = (size_t)B_ * T_ * 2 * H_ * 2;  // bf16 bits
  XT* xp = (XT*)ws;
  ushort* sHA = (ushort*)(ws + xpB);
  ushort* sLA = (ushort*)(ws + xpB + seqB);
  ushort* sHB = (ushort*)(ws + xpB + 2 * seqB);
  ushort* sLB = (ushort*)(ws + xpB + 3 * seqB);
  ushort* WhiT = (ushort*)(ws + xpB + 4 * seqB);
  ushort* WloT = WhiT + (size_t)768 * K_;
  float* fin = (float*)(ws + xpB + 4 * seqB + (size_t)2 * 768 * K_ * 2);

  convX_kernel<<<4096, 256, 0, stream>>>(x, sHB, sLB);

  const ushort* AHs[3] = {sHB, sHA, sHB};
  const ushort* ALs[3] = {sLB, sLA, sLB};
  ushort* oH[3] = {sHA, sHB, nullptr};
  ushort* oL[3] = {sLA, sLB, nullptr};

  for (int l = 0; l < 3; ++l) {
    const float* Wl = Ws + (size_t)l * 2 * K_ * G_;
    const float* bl = bs + (size_t)l * 4 * G_;
    const float* Ul = Us + (size_t)l * 2 * H_ * G_;
    convW_kernel<<<768, 256, 0, stream>>>(Wl, WhiT, WloT);
    gemm3_kernel<XT><<<dim3(M_ / 128, 6), 256, 0, stream>>>(
        AHs[l], ALs[l], WhiT, WloT, bl, xp);
    if (l < 2)
      rec_kernel<XT, false><<<dim3(B_, 2), 384, 0, stream>>>(
          xp, Ul, bl, oH[l], oL[l], nullptr);
    else
      rec_kernel<XT, true><<<dim3(B_, 2), 384, 0, stream>>>(
          xp, Ul, bl, nullptr, nullptr, fin);
  }
  dense_kernel<<<1, B_, 0, stream>>>(fin, Wd, bd, out);
}

extern "C" void kernel_launch(void* const* d_in, const int* in_sizes, int n_in,
                              void* d_out, int out_size, void* d_ws,
                              size_t ws_size, hipStream_t stream) {
  const float* x = (const float*)d_in[0];
  const float* Ws = (const float*)d_in[1];
  const float* Us = (const float*)d_in[2];
  const float* bs = (const float*)d_in[3];
  const float* Wd = (const float*)d_in[4];
  const float* bd = (const float*)d_in[5];
  float* out = (float*)d_out;
  char* ws = (char*)d_ws;

  const size_t seqB = (size_t)B_ * T_ * 2 * H_ * 2;
  const size_t wtB = (size_t)2 * 768 * K_ * 2;
  const size_t finB = (size_t)B_ * 2 * H_ * 4;
  const size_t xp32 = (size_t)2 * T_ * B_ * G_ * 4;
  const size_t tierA = xp32 + 4 * seqB + wtB + finB;      // ~641 MiB, fp32 xp
  if (ws_size >= tierA)
    run_model<float>(x, Ws, Us, bs, Wd, bd, out, ws, stream);
  else
    run_model<bf16>(x, Ws, Us, bs, Wd, bd, out, ws, stream);
}

// Round 4
// 3127.756 us; speedup vs baseline: 1.0174x; 1.0174x over previous
//
#include <hip/hip_runtime.h>
#include <hip/hip_bf16.h>

#define DEV __device__ __forceinline__

constexpr int B_ = 256;   // batch
constexpr int T_ = 512;   // time
constexpr int H_ = 128;   // GRU units
constexpr int K_ = 256;   // input dim per layer (D = 2H = 256 for all layers)
constexpr int G_ = 384;   // 3H
constexpr int M_ = B_ * T_;
constexpr int LDSROW = 72;  // ushorts per LDS tile row (64 data + 8 pad)

using bf16 = __hip_bfloat16;
typedef short bf16x8 __attribute__((ext_vector_type(8)));
typedef float f32x4 __attribute__((ext_vector_type(4)));

DEV float tof(float x) { return x; }
DEV float tof(bf16 x) { return __bfloat162float(x); }
DEV void stor(float* p, float v) { *p = v; }
DEV void stor(bf16* p, float v) { *p = __float2bfloat16(v); }

// float -> bf16 bits, round-to-nearest-even
DEV unsigned short f2bs(float f) {
  union { float f; unsigned u; } v;
  v.f = f;
  unsigned r = (v.u + 0x7FFFu + ((v.u >> 16) & 1u)) >> 16;
  return (unsigned short)r;
}
DEV float bs2f(unsigned short s) {
  union { unsigned u; float f; } v;
  v.u = ((unsigned)s) << 16;
  return v.f;
}

DEV float fsigmoid(float x) { return 1.f / (1.f + __expf(-x)); }
DEV float ftanh(float x) {
  x = fminf(20.f, fmaxf(-20.f, x));
  float e = __expf(-2.f * x);
  return (1.f - e) / (1.f + e);
}

// Barrier draining only LDS traffic (lgkmcnt), not global loads/stores.
DEV void barrier_lds() {
  asm volatile("s_waitcnt lgkmcnt(0)\n\ts_barrier" ::: "memory");
}

DEV f32x4 mfma16(bf16x8 a, bf16x8 b, f32x4 c) {
  return __builtin_amdgcn_mfma_f32_16x16x32_bf16(a, b, c, 0, 0, 0);
}

// ---------------------------------------------------------------------------
// convX: split fp32 x[M,256] into bf16 hi/lo arrays (layer-0 GEMM input).
// ---------------------------------------------------------------------------
__global__ __launch_bounds__(256) void convX_kernel(
    const float* __restrict__ x, ushort* __restrict__ hiA,
    ushort* __restrict__ loA) {
  const int n4 = M_ * K_ / 4;
  for (int idx = blockIdx.x * blockDim.x + threadIdx.x; idx < n4;
       idx += gridDim.x * blockDim.x) {
    float4 v = ((const float4*)x)[idx];
    ushort4 h, l;
    h.x = f2bs(v.x); l.x = f2bs(v.x - bs2f(h.x));
    h.y = f2bs(v.y); l.y = f2bs(v.y - bs2f(h.y));
    h.z = f2bs(v.z); l.z = f2bs(v.z - bs2f(h.z));
    h.w = f2bs(v.w); l.w = f2bs(v.w - bs2f(h.w));
    ((ushort4*)hiA)[idx] = h;
    ((ushort4*)loA)[idx] = l;
  }
}

// ---------------------------------------------------------------------------
// convW: W[dir][256][384] fp32 -> W^T hi/lo bf16 [768 ncol][256 k].
// ---------------------------------------------------------------------------
__global__ __launch_bounds__(256) void convW_kernel(
    const float* __restrict__ W, ushort* __restrict__ WhiT,
    ushort* __restrict__ WloT) {
  const int ncol = blockIdx.x;           // 0..767
  const int dir = ncol / G_, j = ncol % G_;
  const int k = threadIdx.x;             // 0..255
  const float f = W[((size_t)dir * K_ + k) * G_ + j];
  const unsigned short hi = f2bs(f);
  WhiT[(size_t)ncol * K_ + k] = hi;
  WloT[(size_t)ncol * K_ + k] = f2bs(f - bs2f(hi));
}

// ---------------------------------------------------------------------------
// gemm3: C[M,768] = A[M,256] @ W^T' + bias, bf16 hi/lo 3-term split MFMA.
// ---------------------------------------------------------------------------
template <typename XT>
__global__ __launch_bounds__(256, 2) void gemm3_kernel(
    const ushort* __restrict__ Ahi, const ushort* __restrict__ Alo,
    const ushort* __restrict__ WhiT, const ushort* __restrict__ WloT,
    const float* __restrict__ bbias, XT* __restrict__ xp) {
  const int m0 = blockIdx.x * 128;
  const int n0 = blockIdx.y * 128;
  const int tid = threadIdx.x;
  const int w = tid >> 6, lane = tid & 63;
  const int wm = w >> 1, wn = w & 1;
  const int col = lane & 15, quad = lane >> 4;

  __shared__ __align__(16) ushort AH[128 * LDSROW];
  __shared__ __align__(16) ushort AL[128 * LDSROW];
  __shared__ __align__(16) ushort BH[128 * LDSROW];
  __shared__ __align__(16) ushort BL[128 * LDSROW];

  f32x4 acc[4][4];
#pragma unroll
  for (int i = 0; i < 4; ++i)
#pragma unroll
    for (int n = 0; n < 4; ++n) acc[i][n] = (f32x4){0.f, 0.f, 0.f, 0.f};

  const ushort* gsrc = (w == 0) ? Ahi : (w == 1) ? Alo : (w == 2) ? WhiT : WloT;
  ushort* lds = (w == 0) ? AH : (w == 1) ? AL : (w == 2) ? BH : BL;
  const int rbase = (w < 2) ? m0 : n0;

  for (int kb = 0; kb < K_; kb += 64) {
#pragma unroll
    for (int q = 0; q < 16; ++q) {
      const int slot = q * 64 + lane;
      const int r = slot >> 3, s = slot & 7;
      bf16x8 v = *(const bf16x8*)(gsrc + (size_t)(rbase + r) * K_ + kb + s * 8);
      *(bf16x8*)&lds[r * LDSROW + s * 8] = v;
    }
    __syncthreads();
#pragma unroll
    for (int z = 0; z < 2; ++z) {
      const int cc8 = (z * 4 + quad) * 8;
      bf16x8 ah[4], al[4], bh[4], bl[4];
#pragma unroll
      for (int i = 0; i < 4; ++i) {
        const int row = wm * 64 + i * 16 + col;
        ah[i] = *(const bf16x8*)&AH[row * LDSROW + cc8];
        al[i] = *(const bf16x8*)&AL[row * LDSROW + cc8];
      }
#pragma unroll
      for (int n = 0; n < 4; ++n) {
        const int row = wn * 64 + n * 16 + col;
        bh[n] = *(const bf16x8*)&BH[row * LDSROW + cc8];
        bl[n] = *(const bf16x8*)&BL[row * LDSROW + cc8];
      }
#pragma unroll
      for (int i = 0; i < 4; ++i)
#pragma unroll
        for (int n = 0; n < 4; ++n) {
          acc[i][n] = mfma16(ah[i], bh[n], acc[i][n]);
          acc[i][n] = mfma16(al[i], bh[n], acc[i][n]);
          acc[i][n] = mfma16(ah[i], bl[n], acc[i][n]);
        }
    }
    __syncthreads();
  }

  const int dir = (n0 >= G_) ? 1 : 0;
#pragma unroll
  for (int n = 0; n < 4; ++n) {
    const int ncol = n0 + wn * 64 + n * 16 + col;
    const int g = ncol - dir * G_;
    const float bv = bbias[dir * 2 * G_ + g];
#pragma unroll
    for (int i = 0; i < 4; ++i) {
      const int mb = m0 + wm * 64 + i * 16 + quad * 4;
#pragma unroll
      for (int r = 0; r < 4; ++r) {
        const int m = mb + r;
        const int bb = m >> 9;          // T_ = 512
        const int t = m & (T_ - 1);
        stor(xp + ((size_t)(dir * T_ + t) * B_ + bb) * G_ + g,
             acc[i][n][r] + bv);
      }
    }
  }
}

// ---------------------------------------------------------------------------
// Recurrence, v3 (MFMA). Grid (16, 2): 16 sequences per block, 512 threads
// (8 waves), one dir per block. Per step: h[16,128] @ U[128,384] on the
// matrix pipe, bf16 hi/lo 3-term split (same scheme as gemm3, which passes).
//
// v2 post-mortem: fp32 U-in-VGPR spilled (VGPR_Count=84 vs 128 needed for U
// alone); compiler won't hold a big pinned fp32 array across a long loop.
// v3 instead holds U as 24 bf16x8 MFMA B-fragments/lane (96 VGPR) that are
// direct mfma operands each iteration; total pressure ~200 < 256 cap
// (8 waves = 2/SIMD, waves_per_eu(2)).
//
// Wave w owns col-tiles {w, w+8, w+16} -> exactly units [16w,16w+16) for all
// three gates z/r/h, so gate math is register-local (acc0/1/2 hold rz/rr/rh
// for 4 seqs x 1 unit per lane). Only h crosses waves: bf16 hi/lo in LDS,
// XOR-swizzled (idx ^ ((s&7)<<3)) for conflict-free b128 reads, double-
// buffered -> ONE barrier per step. fp32 hprev for the z-blend stays in
// registers. MFMA fragment layouts copied verbatim from the proven gemm3:
//   A: row=lane&15, k=(lane>>4)*8..+8 ; B: col=lane&15, same k
//   D: col=lane&15, row=(lane>>4)*4+r
// ---------------------------------------------------------------------------
template <typename XT, bool LAST>
__global__ __attribute__((amdgpu_flat_work_group_size(512, 512),
                          amdgpu_waves_per_eu(2))) void rec_kernel(
    const XT* __restrict__ xp, const float* __restrict__ Ubase,
    const float* __restrict__ bbase, ushort* __restrict__ seqH,
    ushort* __restrict__ seqL, float* __restrict__ fin) {
  const int dir = blockIdx.y;
  const int b0 = blockIdx.x * 16;
  const float* U = Ubase + dir * (H_ * G_);      // [128 k][384 col]
  const float* bh = bbase + dir * (2 * G_) + G_; // recurrent bias [384]
  const int tid = threadIdx.x;
  const int w = tid >> 6;          // wave 0..7
  const int lane = tid & 63;
  const int col16 = lane & 15;     // tile col (= unit offset) / A-row (= seq)
  const int quad = lane >> 4;      // 0..3
  const int u = w * 16 + col16;    // this lane's GRU unit 0..127

  __shared__ __align__(16) ushort hH[2][16 * H_];  // h hi, double-buffered
  __shared__ __align__(16) ushort hL[2][16 * H_];  // h lo

  // --- U fragments (bf16 hi/lo): B-operand for col-tiles j*8+w, k-tile kk ---
  bf16x8 ubh[3][4], ubl[3][4];
#pragma unroll
  for (int j = 0; j < 3; ++j) {
    const int colg = j * H_ + u;                  // gate column (z/r/h block)
#pragma unroll
    for (int kk = 0; kk < 4; ++kk) {
      const int kbase = kk * 32 + quad * 8;
#pragma unroll
      for (int e = 0; e < 8; ++e) {
        const float f = U[(size_t)(kbase + e) * G_ + colg];
        const unsigned short hi = f2bs(f);
        ubh[j][kk][e] = (short)hi;
        ubl[j][kk][e] = (short)f2bs(f - bs2f(hi));
      }
    }
  }

  const float bz = bh[u], br = bh[H_ + u], bg = bh[2 * H_ + u];

  // zero h buffer 0 (both hi and lo): 2 x 2048 ushorts, 512 thr x 8
  {
    const bf16x8 z8 = (bf16x8){0, 0, 0, 0, 0, 0, 0, 0};
    if (tid < 256)
      *(bf16x8*)&hH[0][tid * 8] = z8;
    else
      *(bf16x8*)&hL[0][(tid - 256) * 8] = z8;
  }

  // xp element offsets for this lane's 4 seqs (time-invariant part)
  const XT* xb = xp + (size_t)dir * T_ * B_ * G_;
  int xofs[4];
#pragma unroll
  for (int r = 0; r < 4; ++r) xofs[r] = (b0 + quad * 4 + r) * G_ + u;

  float hprev[4] = {0.f, 0.f, 0.f, 0.f};
  XT xc[4][3];
  {
    const int t0 = dir ? (T_ - 1) : 0;
    const size_t tb = (size_t)t0 * (B_ * G_);
#pragma unroll
    for (int r = 0; r < 4; ++r)
#pragma unroll
      for (int j = 0; j < 3; ++j) xc[r][j] = xb[tb + xofs[r] + j * H_];
  }
  barrier_lds();

  for (int it = 0; it < T_; ++it) {
    const int t = dir ? (T_ - 1 - it) : it;
    const int cur = it & 1, nxt = cur ^ 1;

    // --- A-fragments: h hi/lo for seq=col16, k-chunk=(kk*32+quad*8) ---
    bf16x8 ah[4], al[4];
    const int arow = col16 * H_;
    const int sw = (col16 & 7) << 3;
#pragma unroll
    for (int kk = 0; kk < 4; ++kk) {
      const int aidx = (arow + kk * 32 + quad * 8) ^ sw;
      ah[kk] = *(const bf16x8*)&hH[cur][aidx];
      al[kk] = *(const bf16x8*)&hL[cur][aidx];
    }

    // --- prefetch next step's x (latency hidden under MFMA phase) ---
    XT xn[4][3];
#pragma unroll
    for (int r = 0; r < 4; ++r)
#pragma unroll
      for (int j = 0; j < 3; ++j) xn[r][j] = xc[r][j];
    if (it + 1 < T_) {
      const int tn = dir ? (t - 1) : (t + 1);
      const size_t tb = (size_t)tn * (B_ * G_);
#pragma unroll
      for (int r = 0; r < 4; ++r)
#pragma unroll
        for (int j = 0; j < 3; ++j) xn[r][j] = xb[tb + xofs[r] + j * H_];
    }

    // --- MFMA: 3 gate-tiles x 4 k-tiles x 3 split-terms = 36 ---
    f32x4 acc0 = {0.f, 0.f, 0.f, 0.f};
    f32x4 acc1 = {0.f, 0.f, 0.f, 0.f};
    f32x4 acc2 = {0.f, 0.f, 0.f, 0.f};
#pragma unroll
    for (int kk = 0; kk < 4; ++kk) {
      acc0 = mfma16(ah[kk], ubh[0][kk], acc0);
      acc1 = mfma16(ah[kk], ubh[1][kk], acc1);
      acc2 = mfma16(ah[kk], ubh[2][kk], acc2);
      acc0 = mfma16(al[kk], ubh[0][kk], acc0);
      acc1 = mfma16(al[kk], ubh[1][kk], acc1);
      acc2 = mfma16(al[kk], ubh[2][kk], acc2);
      acc0 = mfma16(ah[kk], ubl[0][kk], acc0);
      acc1 = mfma16(ah[kk], ubl[1][kk], acc1);
      acc2 = mfma16(ah[kk], ubl[2][kk], acc2);
    }

    // --- gates: lane owns (seq=quad*4+r, unit=u), all 3 gate values local ---
#pragma unroll
    for (int r = 0; r < 4; ++r) {
      const float rz = acc0[r] + bz;
      const float rr = acc1[r] + br;
      const float rh = acc2[r] + bg;
      const float z = fsigmoid(tof(xc[r][0]) + rz);
      const float g = fsigmoid(tof(xc[r][1]) + rr);
      const float hhv = ftanh(tof(xc[r][2]) + g * rh);
      const float hn = z * hprev[r] + (1.f - z) * hhv;
      hprev[r] = hn;

      const int s = quad * 4 + r;
      const unsigned short hi = f2bs(hn);
      const unsigned short lo = f2bs(hn - bs2f(hi));
      const int idx = (s * H_ + u) ^ ((s & 7) << 3);
      hH[nxt][idx] = hi;
      hL[nxt][idx] = lo;
      if constexpr (!LAST) {
        const size_t sidx =
            ((size_t)(b0 + s) * T_ + t) * (2 * H_) + dir * H_ + u;
        seqH[sidx] = hi;
        seqL[sidx] = lo;
      }
#pragma unroll
      for (int j = 0; j < 3; ++j) xc[r][j] = xn[r][j];
    }
    barrier_lds();
  }

  if constexpr (LAST) {
#pragma unroll
    for (int r = 0; r < 4; ++r)
      fin[(size_t)(b0 + quad * 4 + r) * (2 * H_) + dir * H_ + u] = hprev[r];
  }
}

// ---------------------------------------------------------------------------
// Dense head: out[b] = sigmoid(fin[b][:] . Wd + bd)
// ---------------------------------------------------------------------------
__global__ void dense_kernel(const float* __restrict__ fin,
                             const float* __restrict__ Wd,
                             const float* __restrict__ bd,
                             float* __restrict__ out) {
  __shared__ float w[2 * H_];
  const int tid = threadIdx.x;
  w[tid] = Wd[tid];
  __syncthreads();
  float s = bd[0];
  const float* row = fin + tid * (2 * H_);
#pragma unroll 8
  for (int jj = 0; jj < 2 * H_; ++jj) s = fmaf(row[jj], w[jj], s);
  out[tid] = 1.f / (1.f + __expf(-s));
}

// ---------------------------------------------------------------------------
template <typename XT>
static void run_model(const float* x, const float* Ws, const float* Us,
                      const float* bs, const float* Wd, const float* bd,
                      float* out, char* ws, hipStream_t stream) {
  const size_t xpB = (size_t)2 * T_ * B_ * G_ * sizeof(XT);
  const size_t seqB = (size_t)B_ * T_ * 2 * H_ * 2;  // bf16 bits
  XT* xp = (XT*)ws;
  ushort* sHA = (ushort*)(ws + xpB);
  ushort* sLA = (ushort*)(ws + xpB + seqB);
  ushort* sHB = (ushort*)(ws + xpB + 2 * seqB);
  ushort* sLB = (ushort*)(ws + xpB + 3 * seqB);
  ushort* WhiT = (ushort*)(ws + xpB + 4 * seqB);
  ushort* WloT = WhiT + (size_t)768 * K_;
  float* fin = (float*)(ws + xpB + 4 * seqB + (size_t)2 * 768 * K_ * 2);

  convX_kernel<<<4096, 256, 0, stream>>>(x, sHB, sLB);

  const ushort* AHs[3] = {sHB, sHA, sHB};
  const ushort* ALs[3] = {sLB, sLA, sLB};
  ushort* oH[3] = {sHA, sHB, nullptr};
  ushort* oL[3] = {sLA, sLB, nullptr};

  for (int l = 0; l < 3; ++l) {
    const float* Wl = Ws + (size_t)l * 2 * K_ * G_;
    const float* bl = bs + (size_t)l * 4 * G_;
    const float* Ul = Us + (size_t)l * 2 * H_ * G_;
    convW_kernel<<<768, 256, 0, stream>>>(Wl, WhiT, WloT);
    gemm3_kernel<XT><<<dim3(M_ / 128, 6), 256, 0, stream>>>(
        AHs[l], ALs[l], WhiT, WloT, bl, xp);
    if (l < 2)
      rec_kernel<XT, false><<<dim3(B_ / 16, 2), 512, 0, stream>>>(
          xp, Ul, bl, oH[l], oL[l], nullptr);
    else
      rec_kernel<XT, true><<<dim3(B_ / 16, 2), 512, 0, stream>>>(
          xp, Ul, bl, nullptr, nullptr, fin);
  }
  dense_kernel<<<1, B_, 0, stream>>>(fin, Wd, bd, out);
}

extern "C" void kernel_launch(void* const* d_in, const int* in_sizes, int n_in,
                              void* d_out, int out_size, void* d_ws,
                              size_t ws_size, hipStream_t stream) {
  const float* x = (const float*)d_in[0];
  const float* Ws = (const float*)d_in[1];
  const float* Us = (const float*)d_in[2];
  const float* bs = (const float*)d_in[3];
  const float* Wd = (const float*)d_in[4];
  const float* bd = (const float*)d_in[5];
  float* out = (float*)d_out;
  char* ws = (char*)d_ws;

  const size_t seqB = (size_t)B_ * T_ * 2 * H_ * 2;
  const size_t wtB = (size_t)2 * 768 * K_ * 2;
  const size_t finB = (size_t)B_ * 2 * H_ * 4;
  const size_t xp32 = (size_t)2 * T_ * B_ * G_ * 4;
  const size_t tierA = xp32 + 4 * seqB + wtB + finB;      // ~641 MiB, fp32 xp
  if (ws_size >= tierA)
    run_model<float>(x, Ws, Us, bs, Wd, bd, out, ws, stream);
  else
    run_model<bf16>(x, Ws, Us, bs, Wd, bd, out, ws, stream);
}